// Round 8
// baseline (174.745 us; speedup 1.0000x reference)
//
#include <hip/hip_runtime.h>
#include <hip/hip_fp16.h>

#define NN 50000
#define EE 800000
#define TE (EE + NN)     // total edges including self loops
#define NB 196           // dst buckets of 256 nodes
#define CHUNK 2048       // edges per bucketize block
#define NBLK ((EE + CHUNK - 1) / CHUNK)   // 391
#define CAP 6144         // max edges per bucket

typedef unsigned int uint;
typedef unsigned short ushort;
typedef __attribute__((ext_vector_type(8))) short bf16x8;
typedef __attribute__((ext_vector_type(4))) float f32x4;

__device__ __forceinline__ float lrelu(float v){ return v > 0.f ? v : 0.2f*v; }
// round-to-nearest-even fp32 -> bf16
__device__ __forceinline__ ushort bf16r(float a){
  uint ua = __float_as_uint(a);
  return (ushort)((ua + 0x7FFFu + ((ua >> 16) & 1u)) >> 16);
}
__device__ __forceinline__ uint pack_bf16(float a, float b){
  return (uint)bf16r(a) | ((uint)bf16r(b) << 16);
}
__device__ __forceinline__ float bf_lo(uint u){ return __uint_as_float(u << 16); }
__device__ __forceinline__ float bf_hi(uint u){ return __uint_as_float(u & 0xFFFF0000u); }

// ---------------- CSR build (bucketed, no per-edge global atomics) ----------------
__global__ __launch_bounds__(256) void k_zero(int* __restrict__ bcnt){
  int t = threadIdx.x;
  if (t < NB) bcnt[t] = 0;
}

__global__ __launch_bounds__(256) void k_bcount(const int* __restrict__ ei, int* __restrict__ bcnt){
  __shared__ int h[NB];
  int t = threadIdx.x;
  if (t < NB) h[t] = 0;
  __syncthreads();
  int base = blockIdx.x * CHUNK;
  int end = base + CHUNK; if (end > EE) end = EE;
  for (int i = base + t; i < end; i += 256)
    atomicAdd(&h[ei[EE + i] >> 8], 1);
  __syncthreads();
  if (t < NB && h[t]) atomicAdd(&bcnt[t], h[t]);
}

__global__ __launch_bounds__(256) void k_bscan2(const int* __restrict__ bcnt,
                                                int* __restrict__ ebase, int* __restrict__ ecur){
  __shared__ int s[256];
  int t = threadIdx.x;
  int v = (t < NB) ? bcnt[t] : 0;
  s[t] = v;
  __syncthreads();
  for (int off = 1; off < 256; off <<= 1){
    int add = (t >= off) ? s[t-off] : 0;
    __syncthreads();
    s[t] += add;
    __syncthreads();
  }
  if (t < NB){ int ex = s[t] - v; ebase[t] = ex; ecur[t] = ex; }
}

__global__ __launch_bounds__(256) void k_bucketize(const int* __restrict__ ei,
                                                   int* __restrict__ ecur, uint* __restrict__ ebuf){
  __shared__ int h[NB];
  __shared__ int sc[256];
  __shared__ int gdelta[NB];
  __shared__ uint P[CHUNK];
  __shared__ int  A[CHUNK];
  int t = threadIdx.x;
  if (t < NB) h[t] = 0;
  __syncthreads();
  int base = blockIdx.x * CHUNK;
  int end = base + CHUNK; if (end > EE) end = EE;
  int bc = end - base;
  int be[8]; int re[8]; uint pe[8];
  #pragma unroll
  for (int q = 0; q < 8; ++q){
    int i = base + t + q*256;
    be[q] = -1;
    if (i < end){
      int s_ = ei[i], d_ = ei[EE + i];
      pe[q] = ((uint)d_ << 16) | (uint)s_;
      int bb = d_ >> 8;
      be[q] = bb;
      re[q] = atomicAdd(&h[bb], 1);
    }
  }
  __syncthreads();
  int v = (t < NB) ? h[t] : 0;
  sc[t] = v;
  __syncthreads();
  for (int off = 1; off < 256; off <<= 1){
    int add = (t >= off) ? sc[t-off] : 0;
    __syncthreads();
    sc[t] += add;
    __syncthreads();
  }
  if (t < NB){
    int lofs = sc[t] - v;
    int g = v ? atomicAdd(&ecur[t], v) : 0;
    gdelta[t] = g - lofs;
    h[t] = lofs;
  }
  __syncthreads();
  #pragma unroll
  for (int q = 0; q < 8; ++q) if (be[q] >= 0){
    int j = h[be[q]] + re[q];
    P[j] = pe[q];
    A[j] = gdelta[be[q]] + j;
  }
  __syncthreads();
  for (int j = t; j < bc; j += 256) ebuf[A[j]] = P[j];
}

__global__ __launch_bounds__(256) void k_csr(const int* __restrict__ bcnt, const int* __restrict__ ebase,
                                             const uint* __restrict__ ebuf,
                                             int* __restrict__ rowptr, ushort* __restrict__ csr,
                                             ushort* __restrict__ csrd){
  __shared__ uint  sbuf[CAP];
  __shared__ ushort rnk[CAP];
  __shared__ int h[256];
  __shared__ int sc[256];
  int b = blockIdx.x, t = threadIdx.x;
  int nd0 = b * 256;
  int ncnt = NN - nd0; if (ncnt > 256) ncnt = 256;
  int cnt = bcnt[b]; if (cnt > CAP) cnt = CAP;
  int e0 = ebase[b];
  int cb = e0 + nd0;
  h[t] = (t < ncnt) ? 1 : 0;
  for (int j = t; j < cnt; j += 256) sbuf[j] = ebuf[e0 + j];
  __syncthreads();
  for (int j = t; j < cnt; j += 256){
    int local = (sbuf[j] >> 16) & 255;
    rnk[j] = (ushort)atomicAdd(&h[local], 1);
  }
  __syncthreads();
  int v = h[t];
  sc[t] = v;
  __syncthreads();
  for (int off = 1; off < 256; off <<= 1){
    int add = (t >= off) ? sc[t-off] : 0;
    __syncthreads();
    sc[t] += add;
    __syncthreads();
  }
  h[t] = sc[t] - v;
  __syncthreads();
  if (t < ncnt){
    int rp = cb + h[t];
    rowptr[nd0 + t] = rp;
    csr[rp]  = (ushort)(nd0 + t);            // self loop at rank 0
    csrd[rp] = (ushort)(nd0 + t);
  }
  if (b == NB-1 && t == 0) rowptr[NN] = TE;
  for (int j = t; j < cnt; j += 256){
    uint p = sbuf[j];
    int local = (p >> 16) & 255;
    int pos = cb + h[local] + (int)rnk[j];
    csr[pos]  = (ushort)(p & 0xFFFFu);
    csrd[pos] = (ushort)(nd0 + local);
  }
}

// ---------------- GEMM1 (MFMA): h1 = x @ W1 (+ fused attention dots), bf16 out ----------------
__global__ __launch_bounds__(256, 3) void k_gemm1(const float* __restrict__ x, const float* __restrict__ W,
    const float* __restrict__ a_src, const float* __restrict__ a_dst,
    uint* __restrict__ h1b, float* __restrict__ al_s, float* __restrict__ al_d){
  __shared__ ushort Wt[128*136];   // [n][k] ~34 KB
  __shared__ ushort Ash[64*136];   // [m][k] ~17 KB
  int tid = threadIdx.x;
  int row0 = blockIdx.x * 64;
  const float4* W4 = (const float4*)W;
  #pragma unroll
  for (int f0 = 0; f0 < 4096; f0 += 256){
    int idx4 = f0 + tid;
    int k = idx4 >> 5;              // W row (input dim)
    int n0 = (idx4 & 31) * 4;       // output cols
    float4 v = W4[idx4];
    Wt[(n0  )*136 + k] = bf16r(v.x);
    Wt[(n0+1)*136 + k] = bf16r(v.y);
    Wt[(n0+2)*136 + k] = bf16r(v.z);
    Wt[(n0+3)*136 + k] = bf16r(v.w);
  }
  const float4* x4 = (const float4*)x;
  #pragma unroll
  for (int f0 = 0; f0 < 2048; f0 += 256){
    int idx4 = f0 + tid;
    int row = idx4 >> 5;
    int q = idx4 & 31;
    float4 v = make_float4(0.f,0.f,0.f,0.f);
    if (row0 + row < NN) v = x4[(size_t)(row0+row)*32 + q];
    *(uint2*)(Ash + row*136 + q*4) = make_uint2(pack_bf16(v.x, v.y), pack_bf16(v.z, v.w));
  }
  __syncthreads();

  int w = tid >> 6, lane = tid & 63;
  int lm = lane & 15, lg = lane >> 4;
  const ushort* Ab = Ash + (w*16 + lm)*136 + lg*8;
  const ushort* Bb = Wt + lm*136 + lg*8;
  f32x4 acc[8];
  #pragma unroll
  for (int i = 0; i < 8; ++i) acc[i] = (f32x4){0.f,0.f,0.f,0.f};
  #pragma unroll
  for (int ks = 0; ks < 4; ++ks){
    bf16x8 af = *(const bf16x8*)(Ab + ks*32);
    #pragma unroll
    for (int ct = 0; ct < 8; ++ct){
      bf16x8 bfr = *(const bf16x8*)(Bb + ct*16*136 + ks*32);
      acc[ct] = __builtin_amdgcn_mfma_f32_16x16x32_bf16(af, bfr, acc[ct], 0, 0, 0);
    }
  }
  int nbase = row0 + w*16 + lg*4;
  float ps[4][4], pd[4][4];
  #pragma unroll
  for (int h = 0; h < 4; ++h)
    #pragma unroll
    for (int r = 0; r < 4; ++r){ ps[h][r] = 0.f; pd[h][r] = 0.f; }
  #pragma unroll
  for (int ct = 0; ct < 8; ++ct){
    int col = ct*16 + lm;
    float ac = a_src[col], dc = a_dst[col];
    #pragma unroll
    for (int r = 0; r < 4; ++r){
      float v = acc[ct][r];
      ps[ct>>1][r] += v*ac;
      pd[ct>>1][r] += v*dc;
      float vp = __shfl_xor(v, 1);
      if ((lm & 1) == 0 && nbase + r < NN)
        h1b[(size_t)(nbase+r)*64 + ct*8 + (lm>>1)] = pack_bf16(v, vp);
    }
  }
  #pragma unroll
  for (int h = 0; h < 4; ++h)
    #pragma unroll
    for (int r = 0; r < 4; ++r){
      float s = ps[h][r], d = pd[h][r];
      s += __shfl_xor(s,1); s += __shfl_xor(s,2); s += __shfl_xor(s,4); s += __shfl_xor(s,8);
      d += __shfl_xor(d,1); d += __shfl_xor(d,2); d += __shfl_xor(d,4); d += __shfl_xor(d,8);
      if (lm == 0 && nbase + r < NN){
        al_s[(nbase+r)*4 + h] = s;
        al_d[(nbase+r)*4 + h] = d;
      }
    }
}

// ---------------- edge weights, layer 1: w1[e] = fp16x4 exp(lrelu(als+ald)) ----------------
__global__ __launch_bounds__(256) void k_alpha1(const ushort* __restrict__ csr, const ushort* __restrict__ csrd,
    const float* __restrict__ al_s, const float* __restrict__ al_d, uint2* __restrict__ w1){
  int e = blockIdx.x*256 + threadIdx.x;
  if (e >= TE) return;
  int s = csr[e], d = csrd[e];
  float4 as = *(const float4*)(al_s + s*4);
  float4 ad = *(const float4*)(al_d + d*4);
  float w0 = __expf(lrelu(as.x + ad.x));
  float w1_ = __expf(lrelu(as.y + ad.y));
  float w2 = __expf(lrelu(as.z + ad.z));
  float w3 = __expf(lrelu(as.w + ad.w));
  __half2 p01 = __floats2half2_rn(w0, w1_);
  __half2 p23 = __floats2half2_rn(w2, w3);
  w1[e] = make_uint2(*(uint*)&p01, *(uint*)&p23);
}

// ---------------- edge weights, layer 2: w2[e] = fp16 ----------------
__global__ __launch_bounds__(256) void k_alpha2(const ushort* __restrict__ csr, const ushort* __restrict__ csrd,
    const float* __restrict__ al_s, const float* __restrict__ al_d, ushort* __restrict__ w2){
  int e = blockIdx.x*256 + threadIdx.x;
  if (e >= TE) return;
  int s = csr[e], d = csrd[e];
  float w = __expf(lrelu(al_s[s] + al_d[d]));
  __half hw = __float2half_rn(w);
  w2[e] = *(ushort*)&hw;
}

// ---------------- layer-1 aggregation: quarter-wave per edge, uint4 rows, fused ELU ----------------
__global__ __launch_bounds__(256) void k_agg1(const int* __restrict__ rowptr, const ushort* __restrict__ csr,
    const uint2* __restrict__ w1, const uint* __restrict__ h1b,
    const float* __restrict__ b1, uint* __restrict__ h2b){
  int wid  = (blockIdx.x*256 + threadIdx.x) >> 6;   // node id (1 wave per node)
  int lane = threadIdx.x & 63;
  if (wid >= NN) return;
  int q  = lane >> 4;                 // quarter 0..3 -> edge rs+q, rs+q+4, ...
  int qi = lane & 15;                 // owns uints 4qi..4qi+3 = channels 8qi..8qi+7
  int h  = qi >> 2;                   // head of those channels
  int hsh = (h & 1) * 16;             // shift to select half within uint
  int rs = rowptr[wid], re = rowptr[wid+1];
  float den = 0.f;
  float c0=0.f,c1=0.f,c2=0.f,c3=0.f,c4=0.f,c5=0.f,c6=0.f,c7=0.f;
  for (int i = rs + q; i < re; i += 4){
    int s = csr[i];
    uint2 wv = w1[i];                              // 4 fp16, broadcast within quarter
    uint4 u = *(const uint4*)(h1b + (size_t)s*64 + qi*4);
    uint wsel = (h & 2) ? wv.y : wv.x;
    ushort us = (ushort)(wsel >> hsh);
    float alpha = __half2float(*(__half*)&us);
    den += alpha;
    c0 += alpha*bf_lo(u.x); c1 += alpha*bf_hi(u.x);
    c2 += alpha*bf_lo(u.y); c3 += alpha*bf_hi(u.y);
    c4 += alpha*bf_lo(u.z); c5 += alpha*bf_hi(u.z);
    c6 += alpha*bf_lo(u.w); c7 += alpha*bf_hi(u.w);
  }
  den += __shfl_xor(den,16); den += __shfl_xor(den,32);
  c0 += __shfl_xor(c0,16); c0 += __shfl_xor(c0,32);
  c1 += __shfl_xor(c1,16); c1 += __shfl_xor(c1,32);
  c2 += __shfl_xor(c2,16); c2 += __shfl_xor(c2,32);
  c3 += __shfl_xor(c3,16); c3 += __shfl_xor(c3,32);
  c4 += __shfl_xor(c4,16); c4 += __shfl_xor(c4,32);
  c5 += __shfl_xor(c5,16); c5 += __shfl_xor(c5,32);
  c6 += __shfl_xor(c6,16); c6 += __shfl_xor(c6,32);
  c7 += __shfl_xor(c7,16); c7 += __shfl_xor(c7,32);
  if (q == 0){
    float inv = 1.f/(den + 1e-16f);
    float4 ba = *(const float4*)(b1 + qi*8);
    float4 bb = *(const float4*)(b1 + qi*8 + 4);
    float o0 = c0*inv + ba.x, o1 = c1*inv + ba.y, o2 = c2*inv + ba.z, o3 = c3*inv + ba.w;
    float o4 = c4*inv + bb.x, o5 = c5*inv + bb.y, o6 = c6*inv + bb.z, o7 = c7*inv + bb.w;
    o0 = o0 > 0.f ? o0 : (__expf(o0) - 1.f);        // ELU fused
    o1 = o1 > 0.f ? o1 : (__expf(o1) - 1.f);
    o2 = o2 > 0.f ? o2 : (__expf(o2) - 1.f);
    o3 = o3 > 0.f ? o3 : (__expf(o3) - 1.f);
    o4 = o4 > 0.f ? o4 : (__expf(o4) - 1.f);
    o5 = o5 > 0.f ? o5 : (__expf(o5) - 1.f);
    o6 = o6 > 0.f ? o6 : (__expf(o6) - 1.f);
    o7 = o7 > 0.f ? o7 : (__expf(o7) - 1.f);
    uint4 ov = make_uint4(pack_bf16(o0,o1), pack_bf16(o2,o3), pack_bf16(o4,o5), pack_bf16(o6,o7));
    *(uint4*)(h2b + (size_t)wid*64 + qi*4) = ov;
  }
}

// ---------------- GEMM2 (MFMA): g = h2 @ W2 (+ fused attention dots), bf16 in/out ----------------
__global__ __launch_bounds__(256, 4) void k_gemm2(const uint* __restrict__ h2b, const float* __restrict__ W,
    const float* __restrict__ a_src, const float* __restrict__ a_dst,
    uint* __restrict__ gb, float* __restrict__ al_s, float* __restrict__ al_d){
  __shared__ ushort Wt[64*136];    // [n][k] ~17 KB
  __shared__ ushort Ash[64*136];   // [m][k] ~17 KB
  int tid = threadIdx.x;
  int row0 = blockIdx.x * 64;
  const float4* W4 = (const float4*)W;
  #pragma unroll
  for (int f0 = 0; f0 < 2048; f0 += 256){
    int idx4 = f0 + tid;
    int k = idx4 >> 4;
    int n0 = (idx4 & 15) * 4;
    float4 v = W4[idx4];
    Wt[(n0  )*136 + k] = bf16r(v.x);
    Wt[(n0+1)*136 + k] = bf16r(v.y);
    Wt[(n0+2)*136 + k] = bf16r(v.z);
    Wt[(n0+3)*136 + k] = bf16r(v.w);
  }
  #pragma unroll
  for (int f0 = 0; f0 < 4096; f0 += 256){
    int idx = f0 + tid;
    int row = idx >> 6;
    int q = idx & 63;
    uint u = 0;
    if (row0 + row < NN) u = h2b[(size_t)(row0+row)*64 + q];
    *(uint*)(Ash + row*136 + q*2) = u;
  }
  __syncthreads();

  int w = tid >> 6, lane = tid & 63;
  int lm = lane & 15, lg = lane >> 4;
  const ushort* Ab = Ash + (w*16 + lm)*136 + lg*8;
  const ushort* Bb = Wt + lm*136 + lg*8;
  f32x4 acc[4];
  #pragma unroll
  for (int i = 0; i < 4; ++i) acc[i] = (f32x4){0.f,0.f,0.f,0.f};
  #pragma unroll
  for (int ks = 0; ks < 4; ++ks){
    bf16x8 af = *(const bf16x8*)(Ab + ks*32);
    #pragma unroll
    for (int ct = 0; ct < 4; ++ct){
      bf16x8 bfr = *(const bf16x8*)(Bb + ct*16*136 + ks*32);
      acc[ct] = __builtin_amdgcn_mfma_f32_16x16x32_bf16(af, bfr, acc[ct], 0, 0, 0);
    }
  }
  int nbase = row0 + w*16 + lg*4;
  float ps[4], pd[4];
  #pragma unroll
  for (int r = 0; r < 4; ++r){ ps[r] = 0.f; pd[r] = 0.f; }
  #pragma unroll
  for (int ct = 0; ct < 4; ++ct){
    int col = ct*16 + lm;
    float ac = a_src[col], dc = a_dst[col];
    #pragma unroll
    for (int r = 0; r < 4; ++r){
      float v = acc[ct][r];
      ps[r] += v*ac;
      pd[r] += v*dc;
      float vp = __shfl_xor(v, 1);
      if ((lm & 1) == 0 && nbase + r < NN)
        gb[(size_t)(nbase+r)*32 + ct*8 + (lm>>1)] = pack_bf16(v, vp);
    }
  }
  #pragma unroll
  for (int r = 0; r < 4; ++r){
    float s = ps[r], d = pd[r];
    s += __shfl_xor(s,1); s += __shfl_xor(s,2); s += __shfl_xor(s,4); s += __shfl_xor(s,8);
    d += __shfl_xor(d,1); d += __shfl_xor(d,2); d += __shfl_xor(d,4); d += __shfl_xor(d,8);
    if (lm == 0 && nbase + r < NN){
      al_s[nbase+r] = s;
      al_d[nbase+r] = d;
    }
  }
}

// ---------------- layer-2 aggregation: quarter-wave per edge, uint2 rows -> d_out ----------------
__global__ __launch_bounds__(256) void k_agg2(const int* __restrict__ rowptr, const ushort* __restrict__ csr,
    const ushort* __restrict__ w2, const uint* __restrict__ gb,
    const float* __restrict__ b2, float* __restrict__ out){
  int wid  = (blockIdx.x*256 + threadIdx.x) >> 6;   // node id (1 wave per node)
  int lane = threadIdx.x & 63;
  if (wid >= NN) return;
  int q  = lane >> 4;                 // quarter 0..3
  int qi = lane & 15;                 // owns uints 2qi,2qi+1 = channels 4qi..4qi+3
  int rs = rowptr[wid], re = rowptr[wid+1];
  float den = 0.f;
  float c0=0.f,c1=0.f,c2=0.f,c3=0.f;
  for (int i = rs + q; i < re; i += 4){
    int s = csr[i];
    ushort wv = w2[i];
    uint2 u = *(const uint2*)(gb + (size_t)s*32 + qi*2);
    float alpha = __half2float(*(__half*)&wv);
    den += alpha;
    c0 += alpha*bf_lo(u.x); c1 += alpha*bf_hi(u.x);
    c2 += alpha*bf_lo(u.y); c3 += alpha*bf_hi(u.y);
  }
  den += __shfl_xor(den,16); den += __shfl_xor(den,32);
  c0 += __shfl_xor(c0,16); c0 += __shfl_xor(c0,32);
  c1 += __shfl_xor(c1,16); c1 += __shfl_xor(c1,32);
  c2 += __shfl_xor(c2,16); c2 += __shfl_xor(c2,32);
  c3 += __shfl_xor(c3,16); c3 += __shfl_xor(c3,32);
  if (q == 0){
    float inv = 1.f/(den + 1e-16f);
    float4 bb = *(const float4*)(b2 + qi*4);
    *(float4*)(out + (size_t)wid*64 + qi*4) =
      make_float4(c0*inv + bb.x, c1*inv + bb.y, c2*inv + bb.z, c3*inv + bb.w);
  }
}

extern "C" void kernel_launch(void* const* d_in, const int* in_sizes, int n_in,
                              void* d_out, int out_size, void* d_ws, size_t ws_size,
                              hipStream_t stream){
  const float* x   = (const float*)d_in[0];
  const int*   ei  = (const int*)d_in[1];
  const float* W1  = (const float*)d_in[2];
  const float* as1 = (const float*)d_in[3];
  const float* ad1 = (const float*)d_in[4];
  const float* b1  = (const float*)d_in[5];
  const float* W2  = (const float*)d_in[6];
  const float* as2 = (const float*)d_in[7];
  const float* ad2 = (const float*)d_in[8];
  const float* b2  = (const float*)d_in[9];
  float* out = (float*)d_out;
  (void)in_sizes; (void)n_in; (void)out_size; (void)ws_size;

  char* p = (char*)d_ws;
  size_t off = 0;
  auto alloc = [&](size_t bytes)->char*{
    char* r = p + off; off += (bytes + 255) & ~size_t(255); return r;
  };
  uint*  h1b   = (uint*)alloc((size_t)NN*64*4);     // bf16-packed [N][128]
  uint*  h2b   = (uint*)alloc((size_t)NN*64*4);     // bf16-packed [N][128]
  uint*  gb    = (uint*)alloc((size_t)NN*32*4);     // bf16-packed [N][64]
  float* al1s  = (float*)alloc((size_t)NN*4*4);
  float* al1d  = (float*)alloc((size_t)NN*4*4);
  float* al2s  = (float*)alloc((size_t)NN*4);
  float* al2d  = (float*)alloc((size_t)NN*4);
  int*   rowptr= (int*)alloc((size_t)(NN+1)*4);
  ushort* csr  = (ushort*)alloc((size_t)TE*2);
  ushort* csrd = (ushort*)alloc((size_t)TE*2);
  uint2* w1    = (uint2*)alloc((size_t)TE*8);       // fp16x4 per edge
  ushort* w2   = (ushort*)alloc((size_t)TE*2);      // fp16 per edge
  uint*  ebuf  = (uint*)alloc((size_t)EE*4);
  int*   bcnt  = (int*)alloc((size_t)NB*4);
  int*   ebase = (int*)alloc((size_t)NB*4);
  int*   ecur  = (int*)alloc((size_t)NB*4);

  k_zero<<<1, 256, 0, stream>>>(bcnt);
  k_bcount<<<NBLK, 256, 0, stream>>>(ei, bcnt);
  k_bscan2<<<1, 256, 0, stream>>>(bcnt, ebase, ecur);
  k_bucketize<<<NBLK, 256, 0, stream>>>(ei, ecur, ebuf);
  k_csr<<<NB, 256, 0, stream>>>(bcnt, ebase, ebuf, rowptr, csr, csrd);
  k_gemm1<<<(NN+63)/64, 256, 0, stream>>>(x, W1, as1, ad1, h1b, al1s, al1d);
  k_alpha1<<<(TE+255)/256, 256, 0, stream>>>(csr, csrd, al1s, al1d, w1);
  k_agg1<<<(NN*64+255)/256, 256, 0, stream>>>(rowptr, csr, w1, h1b, b1, h2b);
  k_gemm2<<<(NN+63)/64, 256, 0, stream>>>(h2b, W2, as2, ad2, gb, al2s, al2d);
  k_alpha2<<<(TE+255)/256, 256, 0, stream>>>(csr, csrd, al2s, al2d, w2);
  k_agg2<<<(NN*64+255)/256, 256, 0, stream>>>(rowptr, csr, w2, gb, b2, out);
}

// Round 9
// 151.742 us; speedup vs baseline: 1.1516x; 1.1516x over previous
//
#include <hip/hip_runtime.h>

#define NN 50000
#define EE 800000
#define NB 196           // dst buckets of 256 nodes
#define CHUNK 2048       // edges per bucketize block
#define NBLK ((EE + CHUNK - 1) / CHUNK)   // 391
#define CAP 6144         // max raw edges per bucket (mean 4082, sd 64 -> +32 sigma)
#define SSTR 6400        // csr stride per bucket: 256 self-loops + CAP

typedef unsigned int uint;
typedef unsigned short ushort;
typedef __attribute__((ext_vector_type(8))) short bf16x8;
typedef __attribute__((ext_vector_type(4))) float f32x4;

__device__ __forceinline__ float lrelu(float v){ return v > 0.f ? v : 0.2f*v; }
// round-to-nearest-even fp32 -> bf16
__device__ __forceinline__ ushort bf16r(float a){
  uint ua = __float_as_uint(a);
  return (ushort)((ua + 0x7FFFu + ((ua >> 16) & 1u)) >> 16);
}
__device__ __forceinline__ uint pack_bf16(float a, float b){
  return (uint)bf16r(a) | ((uint)bf16r(b) << 16);
}
__device__ __forceinline__ float bf_lo(uint u){ return __uint_as_float(u << 16); }
__device__ __forceinline__ float bf_hi(uint u){ return __uint_as_float(u & 0xFFFF0000u); }

// ---------------- CSR build: zero -> bucketize (fixed-stride) -> csr ----------------
__global__ __launch_bounds__(256) void k_zero(int* __restrict__ ecur){
  int t = threadIdx.x;
  if (t < NB) ecur[t] = 0;
}

// scatter edges into per-bucket private regions ebuf[b*CAP ..]; one atomic per (block,bucket)
__global__ __launch_bounds__(256) void k_bucketize(const int* __restrict__ ei,
                                                   int* __restrict__ ecur, uint* __restrict__ ebuf){
  __shared__ int h[NB];          // per-block bucket counts, then reused as local excl offsets
  __shared__ int sc[256];        // scan scratch
  __shared__ int gdelta[NB];     // global slot base - local base per bucket
  __shared__ uint P[CHUNK];      // packed edges, locally bucket-sorted
  __shared__ int  A[CHUNK];      // final global address per sorted slot
  int t = threadIdx.x;
  if (t < NB) h[t] = 0;
  __syncthreads();
  int base = blockIdx.x * CHUNK;
  int end = base + CHUNK; if (end > EE) end = EE;
  int bc = end - base;
  int be[8]; int re[8]; uint pe[8];
  #pragma unroll
  for (int q = 0; q < 8; ++q){
    int i = base + t + q*256;
    be[q] = -1;
    if (i < end){
      int s_ = ei[i], d_ = ei[EE + i];
      pe[q] = ((uint)d_ << 16) | (uint)s_;
      int bb = d_ >> 8;
      be[q] = bb;
      re[q] = atomicAdd(&h[bb], 1);
    }
  }
  __syncthreads();
  int v = (t < NB) ? h[t] : 0;
  sc[t] = v;
  __syncthreads();
  for (int off = 1; off < 256; off <<= 1){
    int add = (t >= off) ? sc[t-off] : 0;
    __syncthreads();
    sc[t] += add;
    __syncthreads();
  }
  if (t < NB){
    int lofs = sc[t] - v;                       // exclusive local base
    int g = v ? atomicAdd(&ecur[t], v) : 0;     // reserve run inside bucket t
    gdelta[t] = t*CAP + g - lofs;
    h[t] = lofs;
  }
  __syncthreads();
  #pragma unroll
  for (int q = 0; q < 8; ++q) if (be[q] >= 0){
    int j = h[be[q]] + re[q];
    P[j] = pe[q];
    A[j] = gdelta[be[q]] + j;
  }
  __syncthreads();
  for (int j = t; j < bc; j += 256) ebuf[A[j]] = P[j];   // consecutive per run
}

// one block per bucket: counting sort by dst_local -> rptr/rend + ushort csr (+self loops)
__global__ __launch_bounds__(256) void k_csr(const int* __restrict__ ecur,
                                             const uint* __restrict__ ebuf,
                                             int* __restrict__ rptr, int* __restrict__ rend,
                                             ushort* __restrict__ csr){
  __shared__ uint  sbuf[CAP];    // 24 KB
  __shared__ ushort rnk[CAP];    // 12 KB
  __shared__ int h[256];
  __shared__ int sc[256];
  int b = blockIdx.x, t = threadIdx.x;
  int nd0 = b * 256;
  int ncnt = NN - nd0; if (ncnt > 256) ncnt = 256;
  int cnt = ecur[b]; if (cnt > CAP) cnt = CAP;
  int e0 = b * CAP;
  int cb = b * SSTR;
  h[t] = (t < ncnt) ? 1 : 0;     // rank 0 reserved for self loop
  for (int j = t; j < cnt; j += 256) sbuf[j] = ebuf[e0 + j];
  __syncthreads();
  for (int j = t; j < cnt; j += 256){
    int local = (sbuf[j] >> 16) & 255;
    rnk[j] = (ushort)atomicAdd(&h[local], 1);
  }
  __syncthreads();
  int v = h[t];                  // 1 + edges of node t (0 if t >= ncnt)
  sc[t] = v;
  __syncthreads();
  for (int off = 1; off < 256; off <<= 1){
    int add = (t >= off) ? sc[t-off] : 0;
    __syncthreads();
    sc[t] += add;
    __syncthreads();
  }
  h[t] = sc[t] - v;              // exclusive per-node offsets
  __syncthreads();
  if (t < ncnt){
    int rs = cb + h[t];
    rptr[nd0 + t] = rs;
    rend[nd0 + t] = rs + v;
    csr[rs] = (ushort)(nd0 + t);             // self loop at rank 0
  }
  for (int j = t; j < cnt; j += 256){
    uint p = sbuf[j];
    int local = (p >> 16) & 255;
    csr[cb + h[local] + (int)rnk[j]] = (ushort)(p & 0xFFFFu);
  }
}

// ---------------- GEMM1 (MFMA): h1 = x @ W1 (+ fused attention dots), bf16 out ----------------
__global__ __launch_bounds__(256, 3) void k_gemm1(const float* __restrict__ x, const float* __restrict__ W,
    const float* __restrict__ a_src, const float* __restrict__ a_dst,
    uint* __restrict__ h1b, float* __restrict__ al_s, float* __restrict__ al_d){
  __shared__ ushort Wt[128*136];   // [n][k] ~34 KB
  __shared__ ushort Ash[64*136];   // [m][k] ~17 KB
  int tid = threadIdx.x;
  int row0 = blockIdx.x * 64;
  const float4* W4 = (const float4*)W;
  #pragma unroll
  for (int f0 = 0; f0 < 4096; f0 += 256){
    int idx4 = f0 + tid;
    int k = idx4 >> 5;              // W row (input dim)
    int n0 = (idx4 & 31) * 4;       // output cols
    float4 v = W4[idx4];
    Wt[(n0  )*136 + k] = bf16r(v.x);
    Wt[(n0+1)*136 + k] = bf16r(v.y);
    Wt[(n0+2)*136 + k] = bf16r(v.z);
    Wt[(n0+3)*136 + k] = bf16r(v.w);
  }
  const float4* x4 = (const float4*)x;
  #pragma unroll
  for (int f0 = 0; f0 < 2048; f0 += 256){
    int idx4 = f0 + tid;
    int row = idx4 >> 5;
    int q = idx4 & 31;
    float4 v = make_float4(0.f,0.f,0.f,0.f);
    if (row0 + row < NN) v = x4[(size_t)(row0+row)*32 + q];
    *(uint2*)(Ash + row*136 + q*4) = make_uint2(pack_bf16(v.x, v.y), pack_bf16(v.z, v.w));
  }
  __syncthreads();

  int w = tid >> 6, lane = tid & 63;
  int lm = lane & 15, lg = lane >> 4;
  const ushort* Ab = Ash + (w*16 + lm)*136 + lg*8;
  const ushort* Bb = Wt + lm*136 + lg*8;
  f32x4 acc[8];
  #pragma unroll
  for (int i = 0; i < 8; ++i) acc[i] = (f32x4){0.f,0.f,0.f,0.f};
  #pragma unroll
  for (int ks = 0; ks < 4; ++ks){
    bf16x8 af = *(const bf16x8*)(Ab + ks*32);
    #pragma unroll
    for (int ct = 0; ct < 8; ++ct){
      bf16x8 bfr = *(const bf16x8*)(Bb + ct*16*136 + ks*32);
      acc[ct] = __builtin_amdgcn_mfma_f32_16x16x32_bf16(af, bfr, acc[ct], 0, 0, 0);
    }
  }
  int nbase = row0 + w*16 + lg*4;
  float ps[4][4], pd[4][4];
  #pragma unroll
  for (int h = 0; h < 4; ++h)
    #pragma unroll
    for (int r = 0; r < 4; ++r){ ps[h][r] = 0.f; pd[h][r] = 0.f; }
  #pragma unroll
  for (int ct = 0; ct < 8; ++ct){
    int col = ct*16 + lm;
    float ac = a_src[col], dc = a_dst[col];
    #pragma unroll
    for (int r = 0; r < 4; ++r){
      float v = acc[ct][r];
      ps[ct>>1][r] += v*ac;
      pd[ct>>1][r] += v*dc;
      float vp = __shfl_xor(v, 1);
      if ((lm & 1) == 0 && nbase + r < NN)
        h1b[(size_t)(nbase+r)*64 + ct*8 + (lm>>1)] = pack_bf16(v, vp);
    }
  }
  #pragma unroll
  for (int h = 0; h < 4; ++h)
    #pragma unroll
    for (int r = 0; r < 4; ++r){
      float s = ps[h][r], d = pd[h][r];
      s += __shfl_xor(s,1); s += __shfl_xor(s,2); s += __shfl_xor(s,4); s += __shfl_xor(s,8);
      d += __shfl_xor(d,1); d += __shfl_xor(d,2); d += __shfl_xor(d,4); d += __shfl_xor(d,8);
      if (lm == 0 && nbase + r < NN){
        al_s[(nbase+r)*4 + h] = s;
        al_d[(nbase+r)*4 + h] = d;
      }
    }
}

// ---------------- layer-1 aggregation: half-wave per edge, uint2 loads, bf16 out ----------------
__global__ __launch_bounds__(256) void k_agg1(const int* __restrict__ rptr, const int* __restrict__ rend,
    const ushort* __restrict__ csr,
    const uint* __restrict__ h1b, const float* __restrict__ al_s, const float* __restrict__ al_d,
    const float* __restrict__ b1, uint* __restrict__ h2b){
  int wid  = (blockIdx.x*256 + threadIdx.x) >> 6;   // node id (1 wave per node)
  int lane = threadIdx.x & 63;
  if (wid >= NN) return;
  int half = lane >> 5;               // 0: even edges, 1: odd edges
  int li   = lane & 31;               // lane owns channels 4li..4li+3
  int h    = li >> 3;                 // head of those channels
  float ad = al_d[wid*4 + h];
  int rs = rptr[wid], re = rend[wid];
  float a0 = 0.f, a1 = 0.f, a2 = 0.f, a3 = 0.f, den = 0.f;
  int i = rs + half;
  for (; i + 2 < re; i += 4){         // two edges per lane per iter
    int s0 = csr[i], s1 = csr[i+2];
    float e0 = al_s[s0*4 + h], e1 = al_s[s1*4 + h];
    uint2 u0 = *(const uint2*)(h1b + (size_t)s0*64 + li*2);
    uint2 u1 = *(const uint2*)(h1b + (size_t)s1*64 + li*2);
    float ex0 = __expf(lrelu(e0 + ad));
    float ex1 = __expf(lrelu(e1 + ad));
    den += ex0 + ex1;
    a0 += ex0*bf_lo(u0.x) + ex1*bf_lo(u1.x);
    a1 += ex0*bf_hi(u0.x) + ex1*bf_hi(u1.x);
    a2 += ex0*bf_lo(u0.y) + ex1*bf_lo(u1.y);
    a3 += ex0*bf_hi(u0.y) + ex1*bf_hi(u1.y);
  }
  for (; i < re; i += 2){
    int s0 = csr[i];
    float ex = __expf(lrelu(al_s[s0*4 + h] + ad));
    uint2 u = *(const uint2*)(h1b + (size_t)s0*64 + li*2);
    den += ex;
    a0 += ex*bf_lo(u.x); a1 += ex*bf_hi(u.x);
    a2 += ex*bf_lo(u.y); a3 += ex*bf_hi(u.y);
  }
  den += __shfl_xor(den, 32);
  a0  += __shfl_xor(a0, 32);
  a1  += __shfl_xor(a1, 32);
  a2  += __shfl_xor(a2, 32);
  a3  += __shfl_xor(a3, 32);
  if (half == 0){
    float inv = 1.f/(den + 1e-16f);
    float4 bb = *(const float4*)(b1 + li*4);
    float o0 = a0*inv + bb.x, o1 = a1*inv + bb.y, o2 = a2*inv + bb.z, o3 = a3*inv + bb.w;
    o0 = o0 > 0.f ? o0 : (__expf(o0) - 1.f);        // ELU fused
    o1 = o1 > 0.f ? o1 : (__expf(o1) - 1.f);
    o2 = o2 > 0.f ? o2 : (__expf(o2) - 1.f);
    o3 = o3 > 0.f ? o3 : (__expf(o3) - 1.f);
    *(uint2*)(h2b + (size_t)wid*64 + li*2) = make_uint2(pack_bf16(o0,o1), pack_bf16(o2,o3));
  }
}

// ---------------- GEMM2 (MFMA): g = h2 @ W2 (+ fused attention dots), bf16 in/out ----------------
__global__ __launch_bounds__(256, 4) void k_gemm2(const uint* __restrict__ h2b, const float* __restrict__ W,
    const float* __restrict__ a_src, const float* __restrict__ a_dst,
    uint* __restrict__ gb, float* __restrict__ al_s, float* __restrict__ al_d){
  __shared__ ushort Wt[64*136];    // [n][k] ~17 KB
  __shared__ ushort Ash[64*136];   // [m][k] ~17 KB
  int tid = threadIdx.x;
  int row0 = blockIdx.x * 64;
  const float4* W4 = (const float4*)W;
  #pragma unroll
  for (int f0 = 0; f0 < 2048; f0 += 256){
    int idx4 = f0 + tid;
    int k = idx4 >> 4;
    int n0 = (idx4 & 15) * 4;
    float4 v = W4[idx4];
    Wt[(n0  )*136 + k] = bf16r(v.x);
    Wt[(n0+1)*136 + k] = bf16r(v.y);
    Wt[(n0+2)*136 + k] = bf16r(v.z);
    Wt[(n0+3)*136 + k] = bf16r(v.w);
  }
  #pragma unroll
  for (int f0 = 0; f0 < 4096; f0 += 256){
    int idx = f0 + tid;
    int row = idx >> 6;
    int q = idx & 63;
    uint u = 0;
    if (row0 + row < NN) u = h2b[(size_t)(row0+row)*64 + q];
    *(uint*)(Ash + row*136 + q*2) = u;
  }
  __syncthreads();

  int w = tid >> 6, lane = tid & 63;
  int lm = lane & 15, lg = lane >> 4;
  const ushort* Ab = Ash + (w*16 + lm)*136 + lg*8;
  const ushort* Bb = Wt + lm*136 + lg*8;
  f32x4 acc[4];
  #pragma unroll
  for (int i = 0; i < 4; ++i) acc[i] = (f32x4){0.f,0.f,0.f,0.f};
  #pragma unroll
  for (int ks = 0; ks < 4; ++ks){
    bf16x8 af = *(const bf16x8*)(Ab + ks*32);
    #pragma unroll
    for (int ct = 0; ct < 4; ++ct){
      bf16x8 bfr = *(const bf16x8*)(Bb + ct*16*136 + ks*32);
      acc[ct] = __builtin_amdgcn_mfma_f32_16x16x32_bf16(af, bfr, acc[ct], 0, 0, 0);
    }
  }
  int nbase = row0 + w*16 + lg*4;
  float ps[4], pd[4];
  #pragma unroll
  for (int r = 0; r < 4; ++r){ ps[r] = 0.f; pd[r] = 0.f; }
  #pragma unroll
  for (int ct = 0; ct < 4; ++ct){
    int col = ct*16 + lm;
    float ac = a_src[col], dc = a_dst[col];
    #pragma unroll
    for (int r = 0; r < 4; ++r){
      float v = acc[ct][r];
      ps[r] += v*ac;
      pd[r] += v*dc;
      float vp = __shfl_xor(v, 1);
      if ((lm & 1) == 0 && nbase + r < NN)
        gb[(size_t)(nbase+r)*32 + ct*8 + (lm>>1)] = pack_bf16(v, vp);
    }
  }
  #pragma unroll
  for (int r = 0; r < 4; ++r){
    float s = ps[r], d = pd[r];
    s += __shfl_xor(s,1); s += __shfl_xor(s,2); s += __shfl_xor(s,4); s += __shfl_xor(s,8);
    d += __shfl_xor(d,1); d += __shfl_xor(d,2); d += __shfl_xor(d,4); d += __shfl_xor(d,8);
    if (lm == 0 && nbase + r < NN){
      al_s[nbase+r] = s;
      al_d[nbase+r] = d;
    }
  }
}

// ---------------- layer-2 aggregation: half-wave per edge, uint loads -> d_out ----------------
__global__ __launch_bounds__(256) void k_agg2(const int* __restrict__ rptr, const int* __restrict__ rend,
    const ushort* __restrict__ csr,
    const uint* __restrict__ gb, const float* __restrict__ al_s, const float* __restrict__ al_d,
    const float* __restrict__ b2, float* __restrict__ out){
  int wid  = (blockIdx.x*256 + threadIdx.x) >> 6;   // node id (1 wave per node)
  int lane = threadIdx.x & 63;
  if (wid >= NN) return;
  int half = lane >> 5;
  int li   = lane & 31;               // lane owns channels 2li, 2li+1
  float ad = al_d[wid];
  int rs = rptr[wid], re = rend[wid];
  float a0 = 0.f, a1 = 0.f, den = 0.f;
  int i = rs + half;
  for (; i + 2 < re; i += 4){
    int s0 = csr[i], s1 = csr[i+2];
    float e0 = al_s[s0], e1 = al_s[s1];
    uint u0 = gb[(size_t)s0*32 + li];
    uint u1 = gb[(size_t)s1*32 + li];
    float ex0 = __expf(lrelu(e0 + ad));
    float ex1 = __expf(lrelu(e1 + ad));
    den += ex0 + ex1;
    a0 += ex0*bf_lo(u0) + ex1*bf_lo(u1);
    a1 += ex0*bf_hi(u0) + ex1*bf_hi(u1);
  }
  for (; i < re; i += 2){
    int s0 = csr[i];
    float ex = __expf(lrelu(al_s[s0] + ad));
    uint u = gb[(size_t)s0*32 + li];
    den += ex;
    a0 += ex*bf_lo(u); a1 += ex*bf_hi(u);
  }
  den += __shfl_xor(den, 32);
  a0  += __shfl_xor(a0, 32);
  a1  += __shfl_xor(a1, 32);
  if (half == 0){
    float inv = 1.f/(den + 1e-16f);
    float2 bb = *(const float2*)(b2 + li*2);
    *(float2*)(out + (size_t)wid*64 + li*2) = make_float2(a0*inv + bb.x, a1*inv + bb.y);
  }
}

extern "C" void kernel_launch(void* const* d_in, const int* in_sizes, int n_in,
                              void* d_out, int out_size, void* d_ws, size_t ws_size,
                              hipStream_t stream){
  const float* x   = (const float*)d_in[0];
  const int*   ei  = (const int*)d_in[1];
  const float* W1  = (const float*)d_in[2];
  const float* as1 = (const float*)d_in[3];
  const float* ad1 = (const float*)d_in[4];
  const float* b1  = (const float*)d_in[5];
  const float* W2  = (const float*)d_in[6];
  const float* as2 = (const float*)d_in[7];
  const float* ad2 = (const float*)d_in[8];
  const float* b2  = (const float*)d_in[9];
  float* out = (float*)d_out;
  (void)in_sizes; (void)n_in; (void)out_size; (void)ws_size;

  char* p = (char*)d_ws;
  size_t off = 0;
  auto alloc = [&](size_t bytes)->char*{
    char* r = p + off; off += (bytes + 255) & ~size_t(255); return r;
  };
  uint*  h1b   = (uint*)alloc((size_t)NN*64*4);     // bf16-packed [N][128]
  uint*  h2b   = (uint*)alloc((size_t)NN*64*4);     // bf16-packed [N][128]
  uint*  gb    = (uint*)alloc((size_t)NN*32*4);     // bf16-packed [N][64]
  float* al1s  = (float*)alloc((size_t)NN*4*4);
  float* al1d  = (float*)alloc((size_t)NN*4*4);
  float* al2s  = (float*)alloc((size_t)NN*4);
  float* al2d  = (float*)alloc((size_t)NN*4);
  int*   rptr  = (int*)alloc((size_t)NN*4);
  int*   rend  = (int*)alloc((size_t)NN*4);
  ushort* csr  = (ushort*)alloc((size_t)NB*SSTR*2); // padded bucket layout
  uint*  ebuf  = (uint*)alloc((size_t)NB*CAP*4);    // padded bucket layout
  int*   ecur  = (int*)alloc((size_t)NB*4);

  k_zero<<<1, 256, 0, stream>>>(ecur);
  k_bucketize<<<NBLK, 256, 0, stream>>>(ei, ecur, ebuf);
  k_csr<<<NB, 256, 0, stream>>>(ecur, ebuf, rptr, rend, csr);
  k_gemm1<<<(NN+63)/64, 256, 0, stream>>>(x, W1, as1, ad1, h1b, al1s, al1d);
  k_agg1<<<(NN*64+255)/256, 256, 0, stream>>>(rptr, rend, csr, h1b, al1s, al1d, b1, h2b);
  k_gemm2<<<(NN+63)/64, 256, 0, stream>>>(h2b, W2, as2, ad2, gb, al2s, al2d);
  k_agg2<<<(NN*64+255)/256, 256, 0, stream>>>(rptr, rend, csr, gb, al2s, al2d, b2, out);
}

// Round 11
// 137.065 us; speedup vs baseline: 1.2749x; 1.1071x over previous
//
#include <hip/hip_runtime.h>

#define NN 50000
#define EE 800000
#define NB 196           // dst buckets of 256 nodes
#define CHUNK 2048       // edges per bucketize block
#define NBLK ((EE + CHUNK - 1) / CHUNK)   // 391
#define CAP 6144         // max raw edges per bucket (mean 4082, sd 64 -> +32 sigma)
#define SSTR 6400        // csr stride per bucket: 256 self-loops + CAP

typedef unsigned int uint;
typedef unsigned short ushort;
typedef __attribute__((ext_vector_type(8))) short bf16x8;
typedef __attribute__((ext_vector_type(4))) float f32x4;

__device__ __forceinline__ float lrelu(float v){ return v > 0.f ? v : 0.2f*v; }
// round-to-nearest-even fp32 -> bf16
__device__ __forceinline__ ushort bf16r(float a){
  uint ua = __float_as_uint(a);
  return (ushort)((ua + 0x7FFFu + ((ua >> 16) & 1u)) >> 16);
}
__device__ __forceinline__ uint pack_bf16(float a, float b){
  return (uint)bf16r(a) | ((uint)bf16r(b) << 16);
}
__device__ __forceinline__ float bf_lo(uint u){ return __uint_as_float(u << 16); }
__device__ __forceinline__ float bf_hi(uint u){ return __uint_as_float(u & 0xFFFF0000u); }

// ---------------- CSR build: zero -> bucketize (fixed-stride) -> csr ----------------
__global__ __launch_bounds__(256) void k_zero(int* __restrict__ ecur){
  int t = threadIdx.x;
  if (t < NB) ecur[t] = 0;
}

// scatter edges into per-bucket private regions ebuf[b*CAP ..]; one atomic per (block,bucket)
__global__ __launch_bounds__(256) void k_bucketize(const int* __restrict__ ei,
                                                   int* __restrict__ ecur, uint* __restrict__ ebuf){
  __shared__ int h[NB];          // per-block bucket counts, then reused as local excl offsets
  __shared__ int sc[256];        // scan scratch
  __shared__ int gdelta[NB];     // global slot base - local base per bucket
  __shared__ uint P[CHUNK];      // packed edges, locally bucket-sorted
  __shared__ int  A[CHUNK];      // final global address per sorted slot
  int t = threadIdx.x;
  if (t < NB) h[t] = 0;
  __syncthreads();
  int base = blockIdx.x * CHUNK;
  int end = base + CHUNK; if (end > EE) end = EE;
  int bc = end - base;
  int be[8]; int re[8]; uint pe[8];
  #pragma unroll
  for (int q = 0; q < 8; ++q){
    int i = base + t + q*256;
    be[q] = -1;
    if (i < end){
      int s_ = ei[i], d_ = ei[EE + i];
      pe[q] = ((uint)d_ << 16) | (uint)s_;
      int bb = d_ >> 8;
      be[q] = bb;
      re[q] = atomicAdd(&h[bb], 1);
    }
  }
  __syncthreads();
  int v = (t < NB) ? h[t] : 0;
  sc[t] = v;
  __syncthreads();
  for (int off = 1; off < 256; off <<= 1){
    int add = (t >= off) ? sc[t-off] : 0;
    __syncthreads();
    sc[t] += add;
    __syncthreads();
  }
  if (t < NB){
    int lofs = sc[t] - v;                       // exclusive local base
    int g = v ? atomicAdd(&ecur[t], v) : 0;     // reserve run inside bucket t
    gdelta[t] = t*CAP + g - lofs;
    h[t] = lofs;
  }
  __syncthreads();
  #pragma unroll
  for (int q = 0; q < 8; ++q) if (be[q] >= 0){
    int j = h[be[q]] + re[q];
    P[j] = pe[q];
    A[j] = gdelta[be[q]] + j;
  }
  __syncthreads();
  for (int j = t; j < bc; j += 256) ebuf[A[j]] = P[j];   // consecutive per run
}

// one block per bucket: counting sort by dst_local -> rptr/rend + ushort csr (+self loops)
__global__ __launch_bounds__(256) void k_csr(const int* __restrict__ ecur,
                                             const uint* __restrict__ ebuf,
                                             int* __restrict__ rptr, int* __restrict__ rend,
                                             ushort* __restrict__ csr){
  __shared__ uint  sbuf[CAP];    // 24 KB
  __shared__ ushort rnk[CAP];    // 12 KB
  __shared__ int h[256];
  __shared__ int sc[256];
  int b = blockIdx.x, t = threadIdx.x;
  int nd0 = b * 256;
  int ncnt = NN - nd0; if (ncnt > 256) ncnt = 256;
  int cnt = ecur[b]; if (cnt > CAP) cnt = CAP;
  int e0 = b * CAP;
  int cb = b * SSTR;
  h[t] = (t < ncnt) ? 1 : 0;     // rank 0 reserved for self loop
  for (int j = t; j < cnt; j += 256) sbuf[j] = ebuf[e0 + j];
  __syncthreads();
  for (int j = t; j < cnt; j += 256){
    int local = (sbuf[j] >> 16) & 255;
    rnk[j] = (ushort)atomicAdd(&h[local], 1);
  }
  __syncthreads();
  int v = h[t];                  // 1 + edges of node t (0 if t >= ncnt)
  sc[t] = v;
  __syncthreads();
  for (int off = 1; off < 256; off <<= 1){
    int add = (t >= off) ? sc[t-off] : 0;
    __syncthreads();
    sc[t] += add;
    __syncthreads();
  }
  h[t] = sc[t] - v;              // exclusive per-node offsets
  __syncthreads();
  if (t < ncnt){
    int rs = cb + h[t];
    rptr[nd0 + t] = rs;
    rend[nd0 + t] = rs + v;
    csr[rs] = (ushort)(nd0 + t);             // self loop at rank 0
  }
  for (int j = t; j < cnt; j += 256){
    uint p = sbuf[j];
    int local = (p >> 16) & 255;
    csr[cb + h[local] + (int)rnk[j]] = (ushort)(p & 0xFFFFu);
  }
}

// ---------------- GEMM1 (MFMA): h1 = x @ W1 (+ fused attention dots), bf16 out ----------------
__global__ __launch_bounds__(256, 3) void k_gemm1(const float* __restrict__ x, const float* __restrict__ W,
    const float* __restrict__ a_src, const float* __restrict__ a_dst,
    uint* __restrict__ h1b, float* __restrict__ al_s, float* __restrict__ al_d){
  __shared__ ushort Wt[128*136];   // [n][k] ~34 KB
  __shared__ ushort Ash[64*136];   // [m][k] ~17 KB
  int tid = threadIdx.x;
  int row0 = blockIdx.x * 64;
  const float4* W4 = (const float4*)W;
  #pragma unroll
  for (int f0 = 0; f0 < 4096; f0 += 256){
    int idx4 = f0 + tid;
    int k = idx4 >> 5;              // W row (input dim)
    int n0 = (idx4 & 31) * 4;       // output cols
    float4 v = W4[idx4];
    Wt[(n0  )*136 + k] = bf16r(v.x);
    Wt[(n0+1)*136 + k] = bf16r(v.y);
    Wt[(n0+2)*136 + k] = bf16r(v.z);
    Wt[(n0+3)*136 + k] = bf16r(v.w);
  }
  const float4* x4 = (const float4*)x;
  #pragma unroll
  for (int f0 = 0; f0 < 2048; f0 += 256){
    int idx4 = f0 + tid;
    int row = idx4 >> 5;
    int q = idx4 & 31;
    float4 v = make_float4(0.f,0.f,0.f,0.f);
    if (row0 + row < NN) v = x4[(size_t)(row0+row)*32 + q];
    *(uint2*)(Ash + row*136 + q*4) = make_uint2(pack_bf16(v.x, v.y), pack_bf16(v.z, v.w));
  }
  __syncthreads();

  int w = tid >> 6, lane = tid & 63;
  int lm = lane & 15, lg = lane >> 4;
  const ushort* Ab = Ash + (w*16 + lm)*136 + lg*8;
  const ushort* Bb = Wt + lm*136 + lg*8;
  f32x4 acc[8];
  #pragma unroll
  for (int i = 0; i < 8; ++i) acc[i] = (f32x4){0.f,0.f,0.f,0.f};
  #pragma unroll
  for (int ks = 0; ks < 4; ++ks){
    bf16x8 af = *(const bf16x8*)(Ab + ks*32);
    #pragma unroll
    for (int ct = 0; ct < 8; ++ct){
      bf16x8 bfr = *(const bf16x8*)(Bb + ct*16*136 + ks*32);
      acc[ct] = __builtin_amdgcn_mfma_f32_16x16x32_bf16(af, bfr, acc[ct], 0, 0, 0);
    }
  }
  int nbase = row0 + w*16 + lg*4;
  float ps[4][4], pd[4][4];
  #pragma unroll
  for (int h = 0; h < 4; ++h)
    #pragma unroll
    for (int r = 0; r < 4; ++r){ ps[h][r] = 0.f; pd[h][r] = 0.f; }
  #pragma unroll
  for (int ct = 0; ct < 8; ++ct){
    int col = ct*16 + lm;
    float ac = a_src[col], dc = a_dst[col];
    #pragma unroll
    for (int r = 0; r < 4; ++r){
      float v = acc[ct][r];
      ps[ct>>1][r] += v*ac;
      pd[ct>>1][r] += v*dc;
      float vp = __shfl_xor(v, 1);
      if ((lm & 1) == 0 && nbase + r < NN)
        h1b[(size_t)(nbase+r)*64 + ct*8 + (lm>>1)] = pack_bf16(v, vp);
    }
  }
  #pragma unroll
  for (int h = 0; h < 4; ++h)
    #pragma unroll
    for (int r = 0; r < 4; ++r){
      float s = ps[h][r], d = pd[h][r];
      s += __shfl_xor(s,1); s += __shfl_xor(s,2); s += __shfl_xor(s,4); s += __shfl_xor(s,8);
      d += __shfl_xor(d,1); d += __shfl_xor(d,2); d += __shfl_xor(d,4); d += __shfl_xor(d,8);
      if (lm == 0 && nbase + r < NN){
        al_s[(nbase+r)*4 + h] = s;
        al_d[(nbase+r)*4 + h] = d;
      }
    }
}

// ---------------- layer-1 aggregation: batched csr + wave-uniform shfl ----------------
__global__ __launch_bounds__(256) void k_agg1(const int* __restrict__ rptr, const int* __restrict__ rend,
    const ushort* __restrict__ csr,
    const uint* __restrict__ h1b, const float* __restrict__ al_s, const float* __restrict__ al_d,
    const float* __restrict__ b1, uint* __restrict__ h2b){
  int wid  = (blockIdx.x*256 + threadIdx.x) >> 6;   // node id (1 wave per node)
  int lane = threadIdx.x & 63;
  if (wid >= NN) return;
  int half = lane >> 5;               // 0: even edges, 1: odd edges
  int li   = lane & 31;               // lane owns channels 4li..4li+3 (uints 2li,2li+1)
  int h    = li >> 3;                 // head of those channels
  float ad = al_d[(uint)(wid*4 + h)];
  int rs = rptr[wid];
  int deg = rend[wid] - rs;
  uint rowoff = (uint)(li*2);
  float a0 = 0.f, a1 = 0.f, a2 = 0.f, a3 = 0.f, den = 0.f;
  for (int b0 = 0; b0 < deg; b0 += 64){
    int nb = deg - b0; if (nb > 64) nb = 64;
    int sv = (lane < nb) ? (int)csr[(uint)(rs + b0 + lane)] : 0;   // coalesced batch
    int jj = 0;
    // main: uniform condition (jj, nb wave-uniform) -> every __shfl runs with all 64 lanes active
    for (; jj + 8 <= nb; jj += 8){    // 4 edges per half per iter (8 in flight per wave)
      int j = jj + half;
      int s0 = __shfl(sv, j), s1 = __shfl(sv, j+2), s2 = __shfl(sv, j+4), s3 = __shfl(sv, j+6);
      float e0 = al_s[(uint)(s0*4 + h)];
      float e1 = al_s[(uint)(s1*4 + h)];
      float e2 = al_s[(uint)(s2*4 + h)];
      float e3 = al_s[(uint)(s3*4 + h)];
      uint2 u0 = *(const uint2*)(h1b + (((uint)s0) << 6) + rowoff);
      uint2 u1 = *(const uint2*)(h1b + (((uint)s1) << 6) + rowoff);
      uint2 u2 = *(const uint2*)(h1b + (((uint)s2) << 6) + rowoff);
      uint2 u3 = *(const uint2*)(h1b + (((uint)s3) << 6) + rowoff);
      float x0 = __expf(lrelu(e0 + ad));
      float x1 = __expf(lrelu(e1 + ad));
      float x2 = __expf(lrelu(e2 + ad));
      float x3 = __expf(lrelu(e3 + ad));
      den += x0 + x1 + x2 + x3;
      a0 += x0*bf_lo(u0.x) + x1*bf_lo(u1.x) + x2*bf_lo(u2.x) + x3*bf_lo(u3.x);
      a1 += x0*bf_hi(u0.x) + x1*bf_hi(u1.x) + x2*bf_hi(u2.x) + x3*bf_hi(u3.x);
      a2 += x0*bf_lo(u0.y) + x1*bf_lo(u1.y) + x2*bf_lo(u2.y) + x3*bf_lo(u3.y);
      a3 += x0*bf_hi(u0.y) + x1*bf_hi(u1.y) + x2*bf_hi(u2.y) + x3*bf_hi(u3.y);
    }
    // tail: uniform trip count, per-lane predication (shuffle index clamped to lane 0)
    for (; jj < nb; jj += 2){
      int j = jj + half;
      bool ok = j < nb;
      int s0 = __shfl(sv, ok ? j : 0);
      float e = al_s[(uint)(s0*4 + h)];
      uint2 u = *(const uint2*)(h1b + (((uint)s0) << 6) + rowoff);
      float ex = ok ? __expf(lrelu(e + ad)) : 0.f;
      den += ex;
      a0 += ex*bf_lo(u.x); a1 += ex*bf_hi(u.x);
      a2 += ex*bf_lo(u.y); a3 += ex*bf_hi(u.y);
    }
  }
  den += __shfl_xor(den, 32);
  a0  += __shfl_xor(a0, 32);
  a1  += __shfl_xor(a1, 32);
  a2  += __shfl_xor(a2, 32);
  a3  += __shfl_xor(a3, 32);
  if (half == 0){
    float inv = 1.f/(den + 1e-16f);
    float4 bb = *(const float4*)(b1 + li*4);
    float o0 = a0*inv + bb.x, o1 = a1*inv + bb.y, o2 = a2*inv + bb.z, o3 = a3*inv + bb.w;
    o0 = o0 > 0.f ? o0 : (__expf(o0) - 1.f);        // ELU fused
    o1 = o1 > 0.f ? o1 : (__expf(o1) - 1.f);
    o2 = o2 > 0.f ? o2 : (__expf(o2) - 1.f);
    o3 = o3 > 0.f ? o3 : (__expf(o3) - 1.f);
    *(uint2*)(h2b + (size_t)wid*64 + li*2) = make_uint2(pack_bf16(o0,o1), pack_bf16(o2,o3));
  }
}

// ---------------- GEMM2 (MFMA): g = h2 @ W2 (+ fused attention dots), bf16 in/out ----------------
__global__ __launch_bounds__(256, 4) void k_gemm2(const uint* __restrict__ h2b, const float* __restrict__ W,
    const float* __restrict__ a_src, const float* __restrict__ a_dst,
    uint* __restrict__ gb, float* __restrict__ al_s, float* __restrict__ al_d){
  __shared__ ushort Wt[64*136];    // [n][k] ~17 KB
  __shared__ ushort Ash[64*136];   // [m][k] ~17 KB
  int tid = threadIdx.x;
  int row0 = blockIdx.x * 64;
  const float4* W4 = (const float4*)W;
  #pragma unroll
  for (int f0 = 0; f0 < 2048; f0 += 256){
    int idx4 = f0 + tid;
    int k = idx4 >> 4;
    int n0 = (idx4 & 15) * 4;
    float4 v = W4[idx4];
    Wt[(n0  )*136 + k] = bf16r(v.x);
    Wt[(n0+1)*136 + k] = bf16r(v.y);
    Wt[(n0+2)*136 + k] = bf16r(v.z);
    Wt[(n0+3)*136 + k] = bf16r(v.w);
  }
  #pragma unroll
  for (int f0 = 0; f0 < 4096; f0 += 256){
    int idx = f0 + tid;
    int row = idx >> 6;
    int q = idx & 63;
    uint u = 0;
    if (row0 + row < NN) u = h2b[(size_t)(row0+row)*64 + q];
    *(uint*)(Ash + row*136 + q*2) = u;
  }
  __syncthreads();

  int w = tid >> 6, lane = tid & 63;
  int lm = lane & 15, lg = lane >> 4;
  const ushort* Ab = Ash + (w*16 + lm)*136 + lg*8;
  const ushort* Bb = Wt + lm*136 + lg*8;
  f32x4 acc[4];
  #pragma unroll
  for (int i = 0; i < 4; ++i) acc[i] = (f32x4){0.f,0.f,0.f,0.f};
  #pragma unroll
  for (int ks = 0; ks < 4; ++ks){
    bf16x8 af = *(const bf16x8*)(Ab + ks*32);
    #pragma unroll
    for (int ct = 0; ct < 4; ++ct){
      bf16x8 bfr = *(const bf16x8*)(Bb + ct*16*136 + ks*32);
      acc[ct] = __builtin_amdgcn_mfma_f32_16x16x32_bf16(af, bfr, acc[ct], 0, 0, 0);
    }
  }
  int nbase = row0 + w*16 + lg*4;
  float ps[4], pd[4];
  #pragma unroll
  for (int r = 0; r < 4; ++r){ ps[r] = 0.f; pd[r] = 0.f; }
  #pragma unroll
  for (int ct = 0; ct < 4; ++ct){
    int col = ct*16 + lm;
    float ac = a_src[col], dc = a_dst[col];
    #pragma unroll
    for (int r = 0; r < 4; ++r){
      float v = acc[ct][r];
      ps[r] += v*ac;
      pd[r] += v*dc;
      float vp = __shfl_xor(v, 1);
      if ((lm & 1) == 0 && nbase + r < NN)
        gb[(size_t)(nbase+r)*32 + ct*8 + (lm>>1)] = pack_bf16(v, vp);
    }
  }
  #pragma unroll
  for (int r = 0; r < 4; ++r){
    float s = ps[r], d = pd[r];
    s += __shfl_xor(s,1); s += __shfl_xor(s,2); s += __shfl_xor(s,4); s += __shfl_xor(s,8);
    d += __shfl_xor(d,1); d += __shfl_xor(d,2); d += __shfl_xor(d,4); d += __shfl_xor(d,8);
    if (lm == 0 && nbase + r < NN){
      al_s[nbase+r] = s;
      al_d[nbase+r] = d;
    }
  }
}

// ---------------- layer-2 aggregation: batched csr + wave-uniform shfl -> d_out ----------------
__global__ __launch_bounds__(256) void k_agg2(const int* __restrict__ rptr, const int* __restrict__ rend,
    const ushort* __restrict__ csr,
    const uint* __restrict__ gb, const float* __restrict__ al_s, const float* __restrict__ al_d,
    const float* __restrict__ b2, float* __restrict__ out){
  int wid  = (blockIdx.x*256 + threadIdx.x) >> 6;   // node id (1 wave per node)
  int lane = threadIdx.x & 63;
  if (wid >= NN) return;
  int half = lane >> 5;
  int li   = lane & 31;               // lane owns channels 2li, 2li+1 (uint li)
  float ad = al_d[(uint)wid];
  int rs = rptr[wid];
  int deg = rend[wid] - rs;
  float a0 = 0.f, a1 = 0.f, den = 0.f;
  for (int b0 = 0; b0 < deg; b0 += 64){
    int nb = deg - b0; if (nb > 64) nb = 64;
    int sv = (lane < nb) ? (int)csr[(uint)(rs + b0 + lane)] : 0;
    int jj = 0;
    for (; jj + 8 <= nb; jj += 8){
      int j = jj + half;
      int s0 = __shfl(sv, j), s1 = __shfl(sv, j+2), s2 = __shfl(sv, j+4), s3 = __shfl(sv, j+6);
      float e0 = al_s[(uint)s0];
      float e1 = al_s[(uint)s1];
      float e2 = al_s[(uint)s2];
      float e3 = al_s[(uint)s3];
      uint u0 = gb[(((uint)s0) << 5) + (uint)li];
      uint u1 = gb[(((uint)s1) << 5) + (uint)li];
      uint u2 = gb[(((uint)s2) << 5) + (uint)li];
      uint u3 = gb[(((uint)s3) << 5) + (uint)li];
      float x0 = __expf(lrelu(e0 + ad));
      float x1 = __expf(lrelu(e1 + ad));
      float x2 = __expf(lrelu(e2 + ad));
      float x3 = __expf(lrelu(e3 + ad));
      den += x0 + x1 + x2 + x3;
      a0 += x0*bf_lo(u0) + x1*bf_lo(u1) + x2*bf_lo(u2) + x3*bf_lo(u3);
      a1 += x0*bf_hi(u0) + x1*bf_hi(u1) + x2*bf_hi(u2) + x3*bf_hi(u3);
    }
    for (; jj < nb; jj += 2){
      int j = jj + half;
      bool ok = j < nb;
      int s0 = __shfl(sv, ok ? j : 0);
      float e = al_s[(uint)s0];
      uint u = gb[(((uint)s0) << 5) + (uint)li];
      float ex = ok ? __expf(lrelu(e + ad)) : 0.f;
      den += ex;
      a0 += ex*bf_lo(u); a1 += ex*bf_hi(u);
    }
  }
  den += __shfl_xor(den, 32);
  a0  += __shfl_xor(a0, 32);
  a1  += __shfl_xor(a1, 32);
  if (half == 0){
    float inv = 1.f/(den + 1e-16f);
    float2 bb = *(const float2*)(b2 + li*2);
    *(float2*)(out + (size_t)wid*64 + li*2) = make_float2(a0*inv + bb.x, a1*inv + bb.y);
  }
}

extern "C" void kernel_launch(void* const* d_in, const int* in_sizes, int n_in,
                              void* d_out, int out_size, void* d_ws, size_t ws_size,
                              hipStream_t stream){
  const float* x   = (const float*)d_in[0];
  const int*   ei  = (const int*)d_in[1];
  const float* W1  = (const float*)d_in[2];
  const float* as1 = (const float*)d_in[3];
  const float* ad1 = (const float*)d_in[4];
  const float* b1  = (const float*)d_in[5];
  const float* W2  = (const float*)d_in[6];
  const float* as2 = (const float*)d_in[7];
  const float* ad2 = (const float*)d_in[8];
  const float* b2  = (const float*)d_in[9];
  float* out = (float*)d_out;
  (void)in_sizes; (void)n_in; (void)out_size; (void)ws_size;

  char* p = (char*)d_ws;
  size_t off = 0;
  auto alloc = [&](size_t bytes)->char*{
    char* r = p + off; off += (bytes + 255) & ~size_t(255); return r;
  };
  uint*  h1b   = (uint*)alloc((size_t)NN*64*4);     // bf16-packed [N][128]
  uint*  h2b   = (uint*)alloc((size_t)NN*64*4);     // bf16-packed [N][128]
  uint*  gb    = (uint*)alloc((size_t)NN*32*4);     // bf16-packed [N][64]
  float* al1s  = (float*)alloc((size_t)NN*4*4);
  float* al1d  = (float*)alloc((size_t)NN*4*4);
  float* al2s  = (float*)alloc((size_t)NN*4);
  float* al2d  = (float*)alloc((size_t)NN*4);
  int*   rptr  = (int*)alloc((size_t)NN*4);
  int*   rend  = (int*)alloc((size_t)NN*4);
  ushort* csr  = (ushort*)alloc((size_t)NB*SSTR*2); // padded bucket layout
  uint*  ebuf  = (uint*)alloc((size_t)NB*CAP*4);    // padded bucket layout
  int*   ecur  = (int*)alloc((size_t)NB*4);

  k_zero<<<1, 256, 0, stream>>>(ecur);
  k_bucketize<<<NBLK, 256, 0, stream>>>(ei, ecur, ebuf);
  k_csr<<<NB, 256, 0, stream>>>(ecur, ebuf, rptr, rend, csr);
  k_gemm1<<<(NN+63)/64, 256, 0, stream>>>(x, W1, as1, ad1, h1b, al1s, al1d);
  k_agg1<<<(NN*64+255)/256, 256, 0, stream>>>(rptr, rend, csr, h1b, al1s, al1d, b1, h2b);
  k_gemm2<<<(NN+63)/64, 256, 0, stream>>>(h2b, W2, as2, ad2, gb, al2s, al2d);
  k_agg2<<<(NN*64+255)/256, 256, 0, stream>>>(rptr, rend, csr, gb, al2s, al2d, b2, out);
}

// Round 12
// 129.047 us; speedup vs baseline: 1.3541x; 1.0621x over previous
//
#include <hip/hip_runtime.h>

#define NN 50000
#define EE 800000
#define NB 196           // dst buckets of 256 nodes
#define CHUNK 2048       // edges per bucketize block
#define NBLK ((EE + CHUNK - 1) / CHUNK)   // 391
#define GB1 ((NN + 63) / 64)              // 782 gemm1 blocks
#define CAP 6144         // max raw edges per bucket
#define SSTR 6400        // csr stride per bucket: 256 self-loops + CAP

typedef unsigned int uint;
typedef unsigned short ushort;
typedef __attribute__((ext_vector_type(8))) short bf16x8;
typedef __attribute__((ext_vector_type(4))) float f32x4;

__device__ __forceinline__ float lrelu(float v){ return v > 0.f ? v : 0.2f*v; }
__device__ __forceinline__ ushort bf16r(float a){
  uint ua = __float_as_uint(a);
  return (ushort)((ua + 0x7FFFu + ((ua >> 16) & 1u)) >> 16);
}
__device__ __forceinline__ uint pack_bf16(float a, float b){
  return (uint)bf16r(a) | ((uint)bf16r(b) << 16);
}
__device__ __forceinline__ float bf_lo(uint u){ return __uint_as_float(u << 16); }
__device__ __forceinline__ float bf_hi(uint u){ return __uint_as_float(u & 0xFFFF0000u); }

// ---------------- fused: bucketize (blocks 0..NBLK) || gemm1 (blocks NBLK..) ----------------
union BG1Shared {
  struct { int h[NB]; int sc[256]; int gdelta[NB]; uint P[CHUNK]; int A[CHUNK]; } bk;   // ~18.6 KB
  struct { ushort Wt[128*136]; ushort Ash[64*136]; } gm;                                // ~52.2 KB
};

__global__ __launch_bounds__(256, 3) void k_bg1(const int* __restrict__ ei,
    int* __restrict__ ecur, uint* __restrict__ ebuf,
    const float* __restrict__ x, const float* __restrict__ W,
    const float* __restrict__ a_src, const float* __restrict__ a_dst,
    uint* __restrict__ h1b, float* __restrict__ al_s, float* __restrict__ al_d){
  __shared__ BG1Shared S;
  int t = threadIdx.x;
  if (blockIdx.x < NBLK){
    // ---- bucketize body ----
    if (t < NB) S.bk.h[t] = 0;
    __syncthreads();
    int base = blockIdx.x * CHUNK;
    int end = base + CHUNK; if (end > EE) end = EE;
    int bc = end - base;
    int be[8]; int re[8]; uint pe[8];
    #pragma unroll
    for (int q = 0; q < 8; ++q){
      int i = base + t + q*256;
      be[q] = -1;
      if (i < end){
        int s_ = ei[i], d_ = ei[EE + i];
        pe[q] = ((uint)d_ << 16) | (uint)s_;
        int bb = d_ >> 8;
        be[q] = bb;
        re[q] = atomicAdd(&S.bk.h[bb], 1);
      }
    }
    __syncthreads();
    int v = (t < NB) ? S.bk.h[t] : 0;
    S.bk.sc[t] = v;
    __syncthreads();
    for (int off = 1; off < 256; off <<= 1){
      int add = (t >= off) ? S.bk.sc[t-off] : 0;
      __syncthreads();
      S.bk.sc[t] += add;
      __syncthreads();
    }
    if (t < NB){
      int lofs = S.bk.sc[t] - v;
      int g = v ? atomicAdd(&ecur[t], v) : 0;
      S.bk.gdelta[t] = t*CAP + g - lofs;
      S.bk.h[t] = lofs;
    }
    __syncthreads();
    #pragma unroll
    for (int q = 0; q < 8; ++q) if (be[q] >= 0){
      int j = S.bk.h[be[q]] + re[q];
      S.bk.P[j] = pe[q];
      S.bk.A[j] = S.bk.gdelta[be[q]] + j;
    }
    __syncthreads();
    for (int j = t; j < bc; j += 256) ebuf[S.bk.A[j]] = S.bk.P[j];
    return;
  }
  // ---- gemm1 body ----
  int row0 = (blockIdx.x - NBLK) * 64;
  const float4* W4 = (const float4*)W;
  #pragma unroll
  for (int f0 = 0; f0 < 4096; f0 += 256){
    int idx4 = f0 + t;
    int k = idx4 >> 5;
    int n0 = (idx4 & 31) * 4;
    float4 v = W4[idx4];
    S.gm.Wt[(n0  )*136 + k] = bf16r(v.x);
    S.gm.Wt[(n0+1)*136 + k] = bf16r(v.y);
    S.gm.Wt[(n0+2)*136 + k] = bf16r(v.z);
    S.gm.Wt[(n0+3)*136 + k] = bf16r(v.w);
  }
  const float4* x4 = (const float4*)x;
  #pragma unroll
  for (int f0 = 0; f0 < 2048; f0 += 256){
    int idx4 = f0 + t;
    int row = idx4 >> 5;
    int q = idx4 & 31;
    float4 v = make_float4(0.f,0.f,0.f,0.f);
    if (row0 + row < NN) v = x4[(size_t)(row0+row)*32 + q];
    *(uint2*)(S.gm.Ash + row*136 + q*4) = make_uint2(pack_bf16(v.x, v.y), pack_bf16(v.z, v.w));
  }
  __syncthreads();

  int w = t >> 6, lane = t & 63;
  int lm = lane & 15, lg = lane >> 4;
  const ushort* Ab = S.gm.Ash + (w*16 + lm)*136 + lg*8;
  const ushort* Bb = S.gm.Wt + lm*136 + lg*8;
  f32x4 acc[8];
  #pragma unroll
  for (int i = 0; i < 8; ++i) acc[i] = (f32x4){0.f,0.f,0.f,0.f};
  #pragma unroll
  for (int ks = 0; ks < 4; ++ks){
    bf16x8 af = *(const bf16x8*)(Ab + ks*32);
    #pragma unroll
    for (int ct = 0; ct < 8; ++ct){
      bf16x8 bfr = *(const bf16x8*)(Bb + ct*16*136 + ks*32);
      acc[ct] = __builtin_amdgcn_mfma_f32_16x16x32_bf16(af, bfr, acc[ct], 0, 0, 0);
    }
  }
  int nbase = row0 + w*16 + lg*4;
  float ps[4][4], pd[4][4];
  #pragma unroll
  for (int h = 0; h < 4; ++h)
    #pragma unroll
    for (int r = 0; r < 4; ++r){ ps[h][r] = 0.f; pd[h][r] = 0.f; }
  #pragma unroll
  for (int ct = 0; ct < 8; ++ct){
    int col = ct*16 + lm;
    float ac = a_src[col], dc = a_dst[col];
    #pragma unroll
    for (int r = 0; r < 4; ++r){
      float v = acc[ct][r];
      ps[ct>>1][r] += v*ac;
      pd[ct>>1][r] += v*dc;
      float vp = __shfl_xor(v, 1);
      if ((lm & 1) == 0 && nbase + r < NN)
        h1b[(size_t)(nbase+r)*64 + ct*8 + (lm>>1)] = pack_bf16(v, vp);
    }
  }
  #pragma unroll
  for (int h = 0; h < 4; ++h)
    #pragma unroll
    for (int r = 0; r < 4; ++r){
      float s = ps[h][r], d = pd[h][r];
      s += __shfl_xor(s,1); s += __shfl_xor(s,2); s += __shfl_xor(s,4); s += __shfl_xor(s,8);
      d += __shfl_xor(d,1); d += __shfl_xor(d,2); d += __shfl_xor(d,4); d += __shfl_xor(d,8);
      if (lm == 0 && nbase + r < NN){
        al_s[(nbase+r)*4 + h] = s;
        al_d[(nbase+r)*4 + h] = d;
      }
    }
}

// ---------------- csr: one block per bucket (unchanged) ----------------
__global__ __launch_bounds__(256) void k_csr(const int* __restrict__ ecur,
                                             const uint* __restrict__ ebuf,
                                             int* __restrict__ rptr, int* __restrict__ rend,
                                             ushort* __restrict__ csr){
  __shared__ uint  sbuf[CAP];
  __shared__ ushort rnk[CAP];
  __shared__ int h[256];
  __shared__ int sc[256];
  int b = blockIdx.x, t = threadIdx.x;
  int nd0 = b * 256;
  int ncnt = NN - nd0; if (ncnt > 256) ncnt = 256;
  int cnt = ecur[b]; if (cnt > CAP) cnt = CAP;
  int e0 = b * CAP;
  int cb = b * SSTR;
  h[t] = (t < ncnt) ? 1 : 0;
  for (int j = t; j < cnt; j += 256) sbuf[j] = ebuf[e0 + j];
  __syncthreads();
  for (int j = t; j < cnt; j += 256){
    int local = (sbuf[j] >> 16) & 255;
    rnk[j] = (ushort)atomicAdd(&h[local], 1);
  }
  __syncthreads();
  int v = h[t];
  sc[t] = v;
  __syncthreads();
  for (int off = 1; off < 256; off <<= 1){
    int add = (t >= off) ? sc[t-off] : 0;
    __syncthreads();
    sc[t] += add;
    __syncthreads();
  }
  h[t] = sc[t] - v;
  __syncthreads();
  if (t < ncnt){
    int rs = cb + h[t];
    rptr[nd0 + t] = rs;
    rend[nd0 + t] = rs + v;
    csr[rs] = (ushort)(nd0 + t);
  }
  for (int j = t; j < cnt; j += 256){
    uint p = sbuf[j];
    int local = (p >> 16) & 255;
    csr[cb + h[local] + (int)rnk[j]] = (ushort)(p & 0xFFFFu);
  }
}

// ---------------- fused agg1 + gemm2: 512 thr, 64 nodes/block ----------------
// Phase A: 8 waves x 8 nodes, R11 agg loop, h2 bf16 -> LDS (gemm2 A layout, stride 136)
// Phase B: MFMA g = h2 @ W2 + attention dots (al2 via LDS atomics)
__global__ __launch_bounds__(512, 2) void k_ag12(const int* __restrict__ rptr, const int* __restrict__ rend,
    const ushort* __restrict__ csr,
    const uint* __restrict__ h1b, const float* __restrict__ al1s, const float* __restrict__ al1d,
    const float* __restrict__ b1, const float* __restrict__ W2,
    const float* __restrict__ a2s, const float* __restrict__ a2d,
    uint* __restrict__ gb, float* __restrict__ al2s, float* __restrict__ al2d){
  __shared__ ushort Wt[64*136];    // ~17.4 KB
  __shared__ ushort Ash[64*136];   // ~17.4 KB (h2 tile)
  __shared__ float ssum[64], dsum[64];
  int tid = threadIdx.x;
  int nd0 = blockIdx.x * 64;
  if (tid < 64){ ssum[tid] = 0.f; dsum[tid] = 0.f; }
  // stage W2^T as bf16 [n][k]
  const float4* W4 = (const float4*)W2;
  #pragma unroll
  for (int f0 = 0; f0 < 2048; f0 += 512){
    int idx4 = f0 + tid;
    int k = idx4 >> 4;
    int n0 = (idx4 & 15) * 4;
    float4 v = W4[idx4];
    Wt[(n0  )*136 + k] = bf16r(v.x);
    Wt[(n0+1)*136 + k] = bf16r(v.y);
    Wt[(n0+2)*136 + k] = bf16r(v.z);
    Wt[(n0+3)*136 + k] = bf16r(v.w);
  }
  // ---- phase A: aggregation into LDS ----
  int w = tid >> 6, lane = tid & 63;
  int half = lane >> 5;
  int li   = lane & 31;
  int h    = li >> 3;
  uint rowoff = (uint)(li*2);
  uint* AshU = (uint*)Ash;          // 64 rows x 68 uints
  for (int i = 0; i < 8; ++i){
    int nloc = w*8 + i;
    int wid = nd0 + nloc;
    if (wid >= NN) break;           // wave-uniform
    float ad = al1d[(uint)(wid*4 + h)];
    int rs = rptr[wid];
    int deg = rend[wid] - rs;
    float a0 = 0.f, a1 = 0.f, a2 = 0.f, a3 = 0.f, den = 0.f;
    for (int b0 = 0; b0 < deg; b0 += 64){
      int nb = deg - b0; if (nb > 64) nb = 64;
      int sv = (lane < nb) ? (int)csr[(uint)(rs + b0 + lane)] : 0;
      int jj = 0;
      for (; jj + 8 <= nb; jj += 8){
        int j = jj + half;
        int s0 = __shfl(sv, j), s1 = __shfl(sv, j+2), s2 = __shfl(sv, j+4), s3 = __shfl(sv, j+6);
        float e0 = al1s[(uint)(s0*4 + h)];
        float e1 = al1s[(uint)(s1*4 + h)];
        float e2 = al1s[(uint)(s2*4 + h)];
        float e3 = al1s[(uint)(s3*4 + h)];
        uint2 u0 = *(const uint2*)(h1b + (((uint)s0) << 6) + rowoff);
        uint2 u1 = *(const uint2*)(h1b + (((uint)s1) << 6) + rowoff);
        uint2 u2 = *(const uint2*)(h1b + (((uint)s2) << 6) + rowoff);
        uint2 u3 = *(const uint2*)(h1b + (((uint)s3) << 6) + rowoff);
        float x0 = __expf(lrelu(e0 + ad));
        float x1 = __expf(lrelu(e1 + ad));
        float x2 = __expf(lrelu(e2 + ad));
        float x3 = __expf(lrelu(e3 + ad));
        den += x0 + x1 + x2 + x3;
        a0 += x0*bf_lo(u0.x) + x1*bf_lo(u1.x) + x2*bf_lo(u2.x) + x3*bf_lo(u3.x);
        a1 += x0*bf_hi(u0.x) + x1*bf_hi(u1.x) + x2*bf_hi(u2.x) + x3*bf_hi(u3.x);
        a2 += x0*bf_lo(u0.y) + x1*bf_lo(u1.y) + x2*bf_lo(u2.y) + x3*bf_lo(u3.y);
        a3 += x0*bf_hi(u0.y) + x1*bf_hi(u1.y) + x2*bf_hi(u2.y) + x3*bf_hi(u3.y);
      }
      for (; jj < nb; jj += 2){
        int j = jj + half;
        bool ok = j < nb;
        int s0 = __shfl(sv, ok ? j : 0);
        float e = al1s[(uint)(s0*4 + h)];
        uint2 u = *(const uint2*)(h1b + (((uint)s0) << 6) + rowoff);
        float ex = ok ? __expf(lrelu(e + ad)) : 0.f;
        den += ex;
        a0 += ex*bf_lo(u.x); a1 += ex*bf_hi(u.x);
        a2 += ex*bf_lo(u.y); a3 += ex*bf_hi(u.y);
      }
    }
    den += __shfl_xor(den, 32);
    a0  += __shfl_xor(a0, 32);
    a1  += __shfl_xor(a1, 32);
    a2  += __shfl_xor(a2, 32);
    a3  += __shfl_xor(a3, 32);
    if (half == 0){
      float inv = 1.f/(den + 1e-16f);
      float4 bb = *(const float4*)(b1 + li*4);
      float o0 = a0*inv + bb.x, o1 = a1*inv + bb.y, o2 = a2*inv + bb.z, o3 = a3*inv + bb.w;
      o0 = o0 > 0.f ? o0 : (__expf(o0) - 1.f);      // ELU fused
      o1 = o1 > 0.f ? o1 : (__expf(o1) - 1.f);
      o2 = o2 > 0.f ? o2 : (__expf(o2) - 1.f);
      o3 = o3 > 0.f ? o3 : (__expf(o3) - 1.f);
      *(uint2*)(AshU + nloc*68 + li*2) = make_uint2(pack_bf16(o0,o1), pack_bf16(o2,o3));
    }
  }
  __syncthreads();
  // ---- phase B: MFMA gemm2 on the LDS tile ----
  int lm = lane & 15, lg = lane >> 4;
  int rw = w & 3, cw = w >> 2;      // 4 row-groups x 2 col-groups
  const ushort* Ab = Ash + (rw*16 + lm)*136 + lg*8;
  const ushort* Bb = Wt + (cw*32 + lm)*136 + lg*8;
  f32x4 acc[2];
  acc[0] = (f32x4){0.f,0.f,0.f,0.f};
  acc[1] = (f32x4){0.f,0.f,0.f,0.f};
  #pragma unroll
  for (int ks = 0; ks < 4; ++ks){
    bf16x8 af = *(const bf16x8*)(Ab + ks*32);
    #pragma unroll
    for (int ct = 0; ct < 2; ++ct){
      bf16x8 bfr = *(const bf16x8*)(Bb + ct*16*136 + ks*32);
      acc[ct] = __builtin_amdgcn_mfma_f32_16x16x32_bf16(af, bfr, acc[ct], 0, 0, 0);
    }
  }
  int nbase = nd0 + rw*16 + lg*4;
  float ps[4], pd[4];
  #pragma unroll
  for (int r = 0; r < 4; ++r){ ps[r] = 0.f; pd[r] = 0.f; }
  #pragma unroll
  for (int ct = 0; ct < 2; ++ct){
    int col = cw*32 + ct*16 + lm;
    float ac = a2s[col], dc = a2d[col];
    #pragma unroll
    for (int r = 0; r < 4; ++r){
      float v = acc[ct][r];
      ps[r] += v*ac;
      pd[r] += v*dc;
      float vp = __shfl_xor(v, 1);
      if ((lm & 1) == 0 && nbase + r < NN)
        gb[(size_t)(nbase+r)*32 + cw*16 + ct*8 + (lm>>1)] = pack_bf16(v, vp);
    }
  }
  #pragma unroll
  for (int r = 0; r < 4; ++r){
    float s = ps[r], d = pd[r];
    s += __shfl_xor(s,1); s += __shfl_xor(s,2); s += __shfl_xor(s,4); s += __shfl_xor(s,8);
    d += __shfl_xor(d,1); d += __shfl_xor(d,2); d += __shfl_xor(d,4); d += __shfl_xor(d,8);
    if (lm == 0){
      int nloc = rw*16 + lg*4 + r;
      atomicAdd(&ssum[nloc], s);
      atomicAdd(&dsum[nloc], d);
    }
  }
  __syncthreads();
  if (tid < 64 && nd0 + tid < NN){
    al2s[nd0 + tid] = ssum[tid];
    al2d[nd0 + tid] = dsum[tid];
  }
}

// ---------------- layer-2 aggregation (unchanged R11) -> d_out ----------------
__global__ __launch_bounds__(256) void k_agg2(const int* __restrict__ rptr, const int* __restrict__ rend,
    const ushort* __restrict__ csr,
    const uint* __restrict__ gb, const float* __restrict__ al_s, const float* __restrict__ al_d,
    const float* __restrict__ b2, float* __restrict__ out){
  int wid  = (blockIdx.x*256 + threadIdx.x) >> 6;
  int lane = threadIdx.x & 63;
  if (wid >= NN) return;
  int half = lane >> 5;
  int li   = lane & 31;
  float ad = al_d[(uint)wid];
  int rs = rptr[wid];
  int deg = rend[wid] - rs;
  float a0 = 0.f, a1 = 0.f, den = 0.f;
  for (int b0 = 0; b0 < deg; b0 += 64){
    int nb = deg - b0; if (nb > 64) nb = 64;
    int sv = (lane < nb) ? (int)csr[(uint)(rs + b0 + lane)] : 0;
    int jj = 0;
    for (; jj + 8 <= nb; jj += 8){
      int j = jj + half;
      int s0 = __shfl(sv, j), s1 = __shfl(sv, j+2), s2 = __shfl(sv, j+4), s3 = __shfl(sv, j+6);
      float e0 = al_s[(uint)s0];
      float e1 = al_s[(uint)s1];
      float e2 = al_s[(uint)s2];
      float e3 = al_s[(uint)s3];
      uint u0 = gb[(((uint)s0) << 5) + (uint)li];
      uint u1 = gb[(((uint)s1) << 5) + (uint)li];
      uint u2 = gb[(((uint)s2) << 5) + (uint)li];
      uint u3 = gb[(((uint)s3) << 5) + (uint)li];
      float x0 = __expf(lrelu(e0 + ad));
      float x1 = __expf(lrelu(e1 + ad));
      float x2 = __expf(lrelu(e2 + ad));
      float x3 = __expf(lrelu(e3 + ad));
      den += x0 + x1 + x2 + x3;
      a0 += x0*bf_lo(u0) + x1*bf_lo(u1) + x2*bf_lo(u2) + x3*bf_lo(u3);
      a1 += x0*bf_hi(u0) + x1*bf_hi(u1) + x2*bf_hi(u2) + x3*bf_hi(u3);
    }
    for (; jj < nb; jj += 2){
      int j = jj + half;
      bool ok = j < nb;
      int s0 = __shfl(sv, ok ? j : 0);
      float e = al_s[(uint)s0];
      uint u = gb[(((uint)s0) << 5) + (uint)li];
      float ex = ok ? __expf(lrelu(e + ad)) : 0.f;
      den += ex;
      a0 += ex*bf_lo(u); a1 += ex*bf_hi(u);
    }
  }
  den += __shfl_xor(den, 32);
  a0  += __shfl_xor(a0, 32);
  a1  += __shfl_xor(a1, 32);
  if (half == 0){
    float inv = 1.f/(den + 1e-16f);
    float2 bb = *(const float2*)(b2 + li*2);
    *(float2*)(out + (size_t)wid*64 + li*2) = make_float2(a0*inv + bb.x, a1*inv + bb.y);
  }
}

extern "C" void kernel_launch(void* const* d_in, const int* in_sizes, int n_in,
                              void* d_out, int out_size, void* d_ws, size_t ws_size,
                              hipStream_t stream){
  const float* x   = (const float*)d_in[0];
  const int*   ei  = (const int*)d_in[1];
  const float* W1  = (const float*)d_in[2];
  const float* as1 = (const float*)d_in[3];
  const float* ad1 = (const float*)d_in[4];
  const float* b1  = (const float*)d_in[5];
  const float* W2  = (const float*)d_in[6];
  const float* as2 = (const float*)d_in[7];
  const float* ad2 = (const float*)d_in[8];
  const float* b2  = (const float*)d_in[9];
  float* out = (float*)d_out;
  (void)in_sizes; (void)n_in; (void)out_size; (void)ws_size;

  char* p = (char*)d_ws;
  size_t off = 0;
  auto alloc = [&](size_t bytes)->char*{
    char* r = p + off; off += (bytes + 255) & ~size_t(255); return r;
  };
  uint*  h1b   = (uint*)alloc((size_t)NN*64*4);     // bf16-packed [N][128]
  uint*  gb    = (uint*)alloc((size_t)NN*32*4);     // bf16-packed [N][64]
  float* al1s  = (float*)alloc((size_t)NN*4*4);
  float* al1d  = (float*)alloc((size_t)NN*4*4);
  float* al2s  = (float*)alloc((size_t)NN*4);
  float* al2d  = (float*)alloc((size_t)NN*4);
  int*   rptr  = (int*)alloc((size_t)NN*4);
  int*   rend  = (int*)alloc((size_t)NN*4);
  ushort* csr  = (ushort*)alloc((size_t)NB*SSTR*2); // padded bucket layout
  uint*  ebuf  = (uint*)alloc((size_t)NB*CAP*4);    // padded bucket layout
  int*   ecur  = (int*)alloc((size_t)NB*4);

  hipMemsetAsync(ecur, 0, (size_t)NB*4, stream);
  k_bg1<<<NBLK + GB1, 256, 0, stream>>>(ei, ecur, ebuf, x, W1, as1, ad1, h1b, al1s, al1d);
  k_csr<<<NB, 256, 0, stream>>>(ecur, ebuf, rptr, rend, csr);
  k_ag12<<<GB1, 512, 0, stream>>>(rptr, rend, csr, h1b, al1s, al1d, b1, W2, as2, ad2, gb, al2s, al2d);
  k_agg2<<<(NN*64+255)/256, 256, 0, stream>>>(rptr, rend, csr, gb, al2s, al2d, b2, out);
}